// Round 11
// baseline (401.554 us; speedup 1.0000x reference)
//
#include <hip/hip_runtime.h>
#include <math.h>

// DNA-GNN: N=100000, E=3200000, C=8, HEADS=2, d_head=4, 3 layers.
// glin GROUPS=8, cin=cout=1 => per-channel scale+bias.
//
// Round 10b: protect gather tables from streaming L2 pollution.
//   - nontemporal (nt) loads/stores on ALL edge streams (eidx, ebuf/ssrc)
//     so the fp16 gather tables stay L2-resident.
//     (ext_vector_type int4 for nt loads; HIP_vector_type int4 is rejected)
//   - agg1 writes h1 only to T01; agg2 writes h1+h2 to T3.
//   - phaseAC CH 4096 (LDS ~44KB -> 2-3 WGs/CU).
// Tables: A (N,32B: h0 fp16 + f32 dinv) 3.2MB -> L1 gathers, 1 line/edge
//         T01 (N,32B: h0|h1 fp16) 3.2MB -> L2 gathers; dv[] f32 0.4MB
//         T3 (N,48B: h0|h1|h2 fp16) 4.8MB -> L3 gathers
// Agg: 8 lanes/dst, register acc, shfl_xor reduce, classify fused in L3.

#define SBB   8
#define SBN   256
#define CH    4096
#define CAP   9216

typedef _Float16 half8 __attribute__((ext_vector_type(8)));
typedef int int4v __attribute__((ext_vector_type(4)));

__global__ void __launch_bounds__(256) phaseAC(const int* __restrict__ eidx,
                                               int* __restrict__ gcnt,
                                               int* __restrict__ ebuf,
                                               int E, int NS) {
    __shared__ int sorted_[CH];            // 16KB
    __shared__ unsigned short karr[CH];    // 8KB
    __shared__ int cntS[512];
    __shared__ int lofs[512];
    __shared__ int wbase[512];
    __shared__ int sA[512], sB[512];
    int t = threadIdx.x, b = blockIdx.x;
    int base = b * CH;
    int nEdge = E - base; if (nEdge > CH) nEdge = CH;

    for (int i = t; i < 512; i += 256) cntS[i] = 0;
    __syncthreads();

    int w[16]; short kk[16];
#pragma unroll
    for (int it = 0; it < 4; it++) {
        int e0 = base + (it * 256 + t) * 4;
        if (e0 + 3 < E) {
            int4v s4 = __builtin_nontemporal_load((const int4v*)(eidx + e0));
            int4v d4 = __builtin_nontemporal_load((const int4v*)(eidx + E + e0));
#pragma unroll
            for (int j = 0; j < 4; j++) {
                int idx = it * 4 + j;
                w[idx] = s4[j] | ((d4[j] & (SBN - 1)) << 17);
                kk[idx] = (short)(d4[j] >> SBB);
                atomicAdd(&cntS[kk[idx]], 1);
            }
        } else {
#pragma unroll
            for (int j = 0; j < 4; j++) {
                int e = e0 + j, idx = it * 4 + j;
                if (e < E) {
                    int s = eidx[e], d = eidx[E + e];
                    w[idx] = s | ((d & (SBN - 1)) << 17);
                    kk[idx] = (short)(d >> SBB);
                    atomicAdd(&cntS[kk[idx]], 1);
                } else { w[idx] = 0; kk[idx] = 511; }
            }
        }
    }
    __syncthreads();
    sA[t] = cntS[t]; sA[t + 256] = cntS[t + 256];
    __syncthreads();
    int* sp = sA; int* dp = sB;
    for (int o = 1; o < 512; o <<= 1) {
#pragma unroll
        for (int h = 0; h < 2; h++) {
            int i = t + h * 256;
            int v = sp[i];
            if (i >= o) v += sp[i - o];
            dp[i] = v;
        }
        __syncthreads();
        int* tmp = sp; sp = dp; dp = tmp;
    }
    for (int i = t; i < 512; i += 256) {
        int excl = sp[i] - cntS[i];
        lofs[i] = excl;
        if (i < NS && cntS[i] > 0) {
            int g = atomicAdd(&gcnt[i], cntS[i]);
            wbase[i] = i * CAP + g - excl;
        }
    }
    __syncthreads();
#pragma unroll
    for (int idx = 0; idx < 16; idx++) {
        if (kk[idx] != 511) {
            int p = atomicAdd(&lofs[kk[idx]], 1);
            sorted_[p] = w[idx];
            karr[p] = (unsigned short)kk[idx];
        }
    }
    __syncthreads();
    for (int i = t; i < nEdge; i += 256)
        __builtin_nontemporal_store(sorted_[i], &ebuf[wbase[karr[i]] + i]);
}

// One WG per super: stage region, count 256 dls, scan, dl-sort in place;
// emit packed off (pos | deg<<22), dinv -> A@16 and dv[].
__global__ void super_csr(int* __restrict__ ebuf, const int* __restrict__ gcnt,
                          unsigned int* __restrict__ off, char* __restrict__ A,
                          float* __restrict__ dv, int NS, int n) {
    __shared__ int seg[CAP];
    __shared__ int cnt[SBN];
    __shared__ int fillp[SBN];
    __shared__ int sd[256];
    int t = threadIdx.x, k = blockIdx.x;
    cnt[t] = 0;
    int start = k * CAP;
    int len = gcnt[k];
    __syncthreads();
    for (int i = t; i < len; i += 256) {
        int w = __builtin_nontemporal_load(&ebuf[start + i]);
        seg[i] = w;
        atomicAdd(&cnt[w >> 17], 1);
    }
    __syncthreads();
    int v = cnt[t];
    sd[t] = v; __syncthreads();
    for (int o = 1; o < 256; o <<= 1) {
        int u = 0; if (t >= o) u = sd[t - o];
        __syncthreads(); sd[t] += u; __syncthreads();
    }
    int excl = sd[t] - v;
    fillp[t] = excl;
    int d = (k << SBB) + t;
    if (d < n) {
        off[d] = (unsigned int)(start + excl) | ((unsigned int)v << 22);
        float dvv = rsqrtf((float)(v + 1));   // +1 self-loop
        *(float*)(A + (size_t)d * 32 + 16) = dvv;
        dv[d] = dvv;
    }
    __syncthreads();
    for (int i = t; i < len; i += 256) {
        int w = seg[i];
        int pos = atomicAdd(&fillp[w >> 17], 1);
        __builtin_nontemporal_store(w & 131071, &ebuf[start + pos]);
    }
}

// h0 = relu([emb[nidx], x] @ W1 + b1) -> A, T01(+0), T3(+0)
__global__ void node_init(const float* __restrict__ x, const int* __restrict__ nidx,
                          const float* __restrict__ emb, const float* __restrict__ W1,
                          const float* __restrict__ b1, char* __restrict__ A,
                          char* __restrict__ T01, char* __restrict__ T3, int n) {
    int i = blockIdx.x * blockDim.x + threadIdx.x;
    if (i >= n) return;
    float in[24];
    int ni = nidx[i];
    const float4* ep = (const float4*)(emb + (size_t)ni * 8);
    float4 e0 = ep[0], e1 = ep[1];
    in[0] = e0.x; in[1] = e0.y; in[2] = e0.z; in[3] = e0.w;
    in[4] = e1.x; in[5] = e1.y; in[6] = e1.z; in[7] = e1.w;
    const float4* xp = (const float4*)(x + (size_t)i * 16);
#pragma unroll
    for (int t = 0; t < 4; t++) {
        float4 v = xp[t];
        in[8 + 4 * t + 0] = v.x; in[8 + 4 * t + 1] = v.y;
        in[8 + 4 * t + 2] = v.z; in[8 + 4 * t + 3] = v.w;
    }
    float acc[8];
#pragma unroll
    for (int j = 0; j < 8; j++) acc[j] = b1[j];
#pragma unroll
    for (int t = 0; t < 24; t++) {
        float xv = in[t];
#pragma unroll
        for (int j = 0; j < 8; j++) acc[j] = fmaf(xv, W1[t * 8 + j], acc[j]);
    }
    half8 h;
#pragma unroll
    for (int j = 0; j < 8; j++) h[j] = (_Float16)fmaxf(acc[j], 0.0f);
    *(half8*)(A + (size_t)i * 32) = h;
    *(half8*)(T01 + (size_t)i * 32) = h;
    *(half8*)(T3 + (size_t)i * 48) = h;
}

template <int Li>
__device__ __forceinline__ void attn_out(const float* xs, const float* qv,
                                         const float* __restrict__ wk, const float* __restrict__ bk,
                                         const float* __restrict__ wv, const float* __restrict__ bv,
                                         float* out) {
    float score[2][Li];
#pragma unroll
    for (int l = 0; l < Li; l++) {
#pragma unroll
        for (int h = 0; h < 2; h++) {
            float sc = 0.f;
#pragma unroll
            for (int dd = 0; dd < 4; dd++) {
                int c = h * 4 + dd;
                sc = fmaf(qv[c], fmaf(xs[l * 8 + c], wk[c], bk[c]), sc);
            }
            score[h][l] = 0.5f * sc;
        }
    }
    float attn[2][Li];
#pragma unroll
    for (int h = 0; h < 2; h++) {
        float m = score[h][0];
#pragma unroll
        for (int l = 1; l < Li; l++) m = fmaxf(m, score[h][l]);
        float ssum = 0.f;
#pragma unroll
        for (int l = 0; l < Li; l++) { attn[h][l] = __expf(score[h][l] - m); ssum += attn[h][l]; }
        float inv = 1.0f / ssum;
#pragma unroll
        for (int l = 0; l < Li; l++) attn[h][l] *= inv;
    }
#pragma unroll
    for (int c = 0; c < 8; c++) {
        int h = c >> 2;
        float o = 0.f;
#pragma unroll
        for (int l = 0; l < Li; l++) o = fmaf(attn[h][l], fmaf(xs[l * 8 + c], wv[c], bv[c]), o);
        out[c] = o;
    }
}

// 8 lanes per dst; virtual slot 0 = self-loop; register acc + shfl_xor reduce.
template <int Li, bool LAST>
__global__ void agg_layer(const int* __restrict__ ssrc, const unsigned int* __restrict__ off,
                          const char* __restrict__ A, char* __restrict__ T01,
                          char* __restrict__ T3, const float* __restrict__ dv,
                          const float* __restrict__ wq, const float* __restrict__ bq,
                          const float* __restrict__ wk, const float* __restrict__ bk,
                          const float* __restrict__ wv, const float* __restrict__ bv,
                          const float* __restrict__ W2, const float* __restrict__ b2,
                          float* __restrict__ out, int n) {
    int tid = blockIdx.x * blockDim.x + threadIdx.x;
    int d = tid >> 3, t = tid & 7;
    if (d >= n) return;
    unsigned int ow = off[d];
    int lo = (int)(ow & 0x3FFFFFu), cnt = (int)(ow >> 22);

    half8 qh;
    if (Li == 1) qh = *(const half8*)(A + (size_t)d * 32);
    else if (Li == 2) qh = *(const half8*)(T01 + (size_t)d * 32 + 16);
    else qh = *(const half8*)(T3 + (size_t)d * 48 + 32);
    float qv[8];
#pragma unroll
    for (int c = 0; c < 8; c++) qv[c] = fmaf((float)qh[c], wq[c], bq[c]);

    float acc[8];
#pragma unroll
    for (int c = 0; c < 8; c++) acc[c] = 0.f;

    for (int j = t; j < cnt + 1; j += 8) {
        int s = (j == 0) ? d : __builtin_nontemporal_load(&ssrc[lo + j - 1]);
        float xs[8 * Li];
        float ns;
        if (Li == 1) {
            const char* ab = A + (size_t)s * 32;
            half8 h = *(const half8*)ab;
#pragma unroll
            for (int c = 0; c < 8; c++) xs[c] = (float)h[c];
            ns = *(const float*)(ab + 16);
        } else if (Li == 2) {
            const char* ub = T01 + (size_t)s * 32;
            half8 h0 = *(const half8*)ub;
            half8 h1 = *(const half8*)(ub + 16);
#pragma unroll
            for (int c = 0; c < 8; c++) { xs[c] = (float)h0[c]; xs[8 + c] = (float)h1[c]; }
            ns = dv[s];
        } else {
            const char* ub = T3 + (size_t)s * 48;
#pragma unroll
            for (int l = 0; l < 3; l++) {
                half8 h = *(const half8*)(ub + l * 16);
#pragma unroll
                for (int c = 0; c < 8; c++) xs[l * 8 + c] = (float)h[c];
            }
            ns = dv[s];
        }
        float o[8];
        attn_out<Li>(xs, qv, wk, bk, wv, bv, o);
#pragma unroll
        for (int c = 0; c < 8; c++) acc[c] = fmaf(o[c], ns, acc[c]);
    }
#pragma unroll
    for (int m = 1; m < 8; m <<= 1) {
#pragma unroll
        for (int c = 0; c < 8; c++) acc[c] += __shfl_xor(acc[c], m);
    }
    float nd = (Li == 1) ? *(const float*)(A + (size_t)d * 32 + 16) : dv[d];
    if (!LAST) {
        float h = fmaxf(acc[t] * nd, 0.f);
        _Float16 hh = (_Float16)h;
        if (Li == 1) {
            *(_Float16*)(T01 + (size_t)d * 32 + 16 + 2 * t) = hh;   // h1 -> T01 only
        } else {
            // T3 gets h1 (this layer's q row, in registers) + h2
            *(_Float16*)(T3 + (size_t)d * 48 + 16 + 2 * t) = qh[t];
            *(_Float16*)(T3 + (size_t)d * 48 + 32 + 2 * t) = hh;
        }
    } else if (t == 0) {
        float z0 = b2[0], z1 = b2[1];
#pragma unroll
        for (int c = 0; c < 8; c++) {
            float h = fmaxf(acc[c] * nd, 0.f);
            z0 = fmaf(h, W2[c * 2 + 0], z0);
            z1 = fmaf(h, W2[c * 2 + 1], z1);
        }
        float m = fmaxf(z0, z1);
        float lse = m + logf(__expf(z0 - m) + __expf(z1 - m));
        ((float2*)out)[d] = make_float2(z0 - lse, z1 - lse);
    }
}

extern "C" void kernel_launch(void* const* d_in, const int* in_sizes, int n_in,
                              void* d_out, int out_size, void* d_ws, size_t ws_size,
                              hipStream_t stream) {
    const float* x    = (const float*)d_in[0];
    const int*   nidx = (const int*)d_in[1];
    const int*   eidx = (const int*)d_in[3];
    const float* emb  = (const float*)d_in[5];
    const float* W1   = (const float*)d_in[6];
    const float* b1   = (const float*)d_in[7];
    const float* Wq   = (const float*)d_in[8];
    const float* bq   = (const float*)d_in[9];
    const float* Wk   = (const float*)d_in[10];
    const float* bk   = (const float*)d_in[11];
    const float* Wv   = (const float*)d_in[12];
    const float* bv   = (const float*)d_in[13];
    const float* W2   = (const float*)d_in[14];
    const float* b2   = (const float*)d_in[15];
    float* out = (float*)d_out;

    const int n = in_sizes[0] / 16;            // 100000
    const int E = in_sizes[3] / 2;             // 3200000
    const int NS = (n + SBN - 1) / SBN;        // 391
    const int NBLK = (E + CH - 1) / CH;        // 782

    char* wsp = (char*)d_ws;
    char*  A     = wsp;                      wsp += (size_t)n * 32;
    char*  T01   = wsp;                      wsp += (size_t)n * 32;
    char*  T3    = wsp;                      wsp += (size_t)n * 48;
    float* dv    = (float*)wsp;              wsp += (size_t)n * 4;
    int*   ebuf  = (int*)wsp;                wsp += (size_t)NS * CAP * 4;
    unsigned int* off = (unsigned int*)wsp;  wsp += (size_t)n * 4;
    int*   gcnt  = (int*)wsp;                wsp += (size_t)NS * 4;

    dim3 blk(256);
    dim3 gn((n + 255) / 256);
    dim3 ga(((size_t)n * 8 + 255) / 256);

    (void)hipMemsetAsync(gcnt, 0, (size_t)NS * 4, stream);
    phaseAC<<<NBLK, blk, 0, stream>>>(eidx, gcnt, ebuf, E, NS);
    super_csr<<<NS, blk, 0, stream>>>(ebuf, gcnt, off, A, dv, NS, n);
    node_init<<<gn, blk, 0, stream>>>(x, nidx, emb, W1, b1, A, T01, T3, n);

    agg_layer<1, false><<<ga, blk, 0, stream>>>(ebuf, off, A, T01, T3, dv,
        Wq, bq, Wk, bk, Wv, bv, W2, b2, out, n);
    agg_layer<2, false><<<ga, blk, 0, stream>>>(ebuf, off, A, T01, T3, dv,
        Wq + 8, bq + 8, Wk + 8, bk + 8, Wv + 8, bv + 8, W2, b2, out, n);
    agg_layer<3, true><<<ga, blk, 0, stream>>>(ebuf, off, A, T01, T3, dv,
        Wq + 16, bq + 16, Wk + 16, bk + 16, Wv + 16, bv + 16, W2, b2, out, n);
}

// Round 12
// 319.521 us; speedup vs baseline: 1.2567x; 1.2567x over previous
//
#include <hip/hip_runtime.h>
#include <math.h>

// DNA-GNN: N=100000, E=3200000, C=8, HEADS=2, d_head=4, 3 layers.
// glin GROUPS=8, cin=cout=1 => per-channel scale+bias.
//
// Round 12: r11 minus the nt-store mistake.
//   - nt LOADS kept on pure streams (eidx, ebuf staging read, ssrc in agg):
//     they are never re-read, so skipping L2 allocation protects the tables.
//   - nt STORES reverted to plain stores: super_csr's scattered dl-sort
//     writes and phaseAC's short-run write-out must be absorbed by L2
//     (r11 nt stores wrote through: WRITE_SIZE 26->225MB, super_csr 25->117us).
// Tables: A (N,32B: h0 fp16 + f32 dinv) 3.2MB -> L1 gathers
//         T01 (N,32B: h0|h1 fp16) 3.2MB -> L2 gathers; dv[] f32 0.4MB
//         T3 (N,48B: h0|h1|h2 fp16) 4.8MB -> L3 gathers
// Agg: 8 lanes/dst, register acc, shfl_xor reduce, classify fused in L3.

#define SBB   8
#define SBN   256
#define CH    4096
#define CAP   9216

typedef _Float16 half8 __attribute__((ext_vector_type(8)));
typedef int int4v __attribute__((ext_vector_type(4)));

__global__ void __launch_bounds__(256) phaseAC(const int* __restrict__ eidx,
                                               int* __restrict__ gcnt,
                                               int* __restrict__ ebuf,
                                               int E, int NS) {
    __shared__ int sorted_[CH];            // 16KB
    __shared__ unsigned short karr[CH];    // 8KB
    __shared__ int cntS[512];
    __shared__ int lofs[512];
    __shared__ int wbase[512];
    __shared__ int sA[512], sB[512];
    int t = threadIdx.x, b = blockIdx.x;
    int base = b * CH;
    int nEdge = E - base; if (nEdge > CH) nEdge = CH;

    for (int i = t; i < 512; i += 256) cntS[i] = 0;
    __syncthreads();

    int w[16]; short kk[16];
#pragma unroll
    for (int it = 0; it < 4; it++) {
        int e0 = base + (it * 256 + t) * 4;
        if (e0 + 3 < E) {
            int4v s4 = __builtin_nontemporal_load((const int4v*)(eidx + e0));
            int4v d4 = __builtin_nontemporal_load((const int4v*)(eidx + E + e0));
#pragma unroll
            for (int j = 0; j < 4; j++) {
                int idx = it * 4 + j;
                w[idx] = s4[j] | ((d4[j] & (SBN - 1)) << 17);
                kk[idx] = (short)(d4[j] >> SBB);
                atomicAdd(&cntS[kk[idx]], 1);
            }
        } else {
#pragma unroll
            for (int j = 0; j < 4; j++) {
                int e = e0 + j, idx = it * 4 + j;
                if (e < E) {
                    int s = eidx[e], d = eidx[E + e];
                    w[idx] = s | ((d & (SBN - 1)) << 17);
                    kk[idx] = (short)(d >> SBB);
                    atomicAdd(&cntS[kk[idx]], 1);
                } else { w[idx] = 0; kk[idx] = 511; }
            }
        }
    }
    __syncthreads();
    sA[t] = cntS[t]; sA[t + 256] = cntS[t + 256];
    __syncthreads();
    int* sp = sA; int* dp = sB;
    for (int o = 1; o < 512; o <<= 1) {
#pragma unroll
        for (int h = 0; h < 2; h++) {
            int i = t + h * 256;
            int v = sp[i];
            if (i >= o) v += sp[i - o];
            dp[i] = v;
        }
        __syncthreads();
        int* tmp = sp; sp = dp; dp = tmp;
    }
    for (int i = t; i < 512; i += 256) {
        int excl = sp[i] - cntS[i];
        lofs[i] = excl;
        if (i < NS && cntS[i] > 0) {
            int g = atomicAdd(&gcnt[i], cntS[i]);
            wbase[i] = i * CAP + g - excl;
        }
    }
    __syncthreads();
#pragma unroll
    for (int idx = 0; idx < 16; idx++) {
        if (kk[idx] != 511) {
            int p = atomicAdd(&lofs[kk[idx]], 1);
            sorted_[p] = w[idx];
            karr[p] = (unsigned short)kk[idx];
        }
    }
    __syncthreads();
    for (int i = t; i < nEdge; i += 256)
        ebuf[wbase[karr[i]] + i] = sorted_[i];     // plain store: L2-absorbed
}

// One WG per super: stage region, count 256 dls, scan, dl-sort in place;
// emit packed off (pos | deg<<22), dinv -> A@16 and dv[].
__global__ void super_csr(int* __restrict__ ebuf, const int* __restrict__ gcnt,
                          unsigned int* __restrict__ off, char* __restrict__ A,
                          float* __restrict__ dv, int NS, int n) {
    __shared__ int seg[CAP];
    __shared__ int cnt[SBN];
    __shared__ int fillp[SBN];
    __shared__ int sd[256];
    int t = threadIdx.x, k = blockIdx.x;
    cnt[t] = 0;
    int start = k * CAP;
    int len = gcnt[k];
    __syncthreads();
    for (int i = t; i < len; i += 256) {
        int w = __builtin_nontemporal_load(&ebuf[start + i]);
        seg[i] = w;
        atomicAdd(&cnt[w >> 17], 1);
    }
    __syncthreads();
    int v = cnt[t];
    sd[t] = v; __syncthreads();
    for (int o = 1; o < 256; o <<= 1) {
        int u = 0; if (t >= o) u = sd[t - o];
        __syncthreads(); sd[t] += u; __syncthreads();
    }
    int excl = sd[t] - v;
    fillp[t] = excl;
    int d = (k << SBB) + t;
    if (d < n) {
        off[d] = (unsigned int)(start + excl) | ((unsigned int)v << 22);
        float dvv = rsqrtf((float)(v + 1));   // +1 self-loop
        *(float*)(A + (size_t)d * 32 + 16) = dvv;
        dv[d] = dvv;
    }
    __syncthreads();
    for (int i = t; i < len; i += 256) {
        int w = seg[i];
        int pos = atomicAdd(&fillp[w >> 17], 1);
        ebuf[start + pos] = w & 131071;            // plain store: L2-absorbed
    }
}

// h0 = relu([emb[nidx], x] @ W1 + b1) -> A, T01(+0), T3(+0)
__global__ void node_init(const float* __restrict__ x, const int* __restrict__ nidx,
                          const float* __restrict__ emb, const float* __restrict__ W1,
                          const float* __restrict__ b1, char* __restrict__ A,
                          char* __restrict__ T01, char* __restrict__ T3, int n) {
    int i = blockIdx.x * blockDim.x + threadIdx.x;
    if (i >= n) return;
    float in[24];
    int ni = nidx[i];
    const float4* ep = (const float4*)(emb + (size_t)ni * 8);
    float4 e0 = ep[0], e1 = ep[1];
    in[0] = e0.x; in[1] = e0.y; in[2] = e0.z; in[3] = e0.w;
    in[4] = e1.x; in[5] = e1.y; in[6] = e1.z; in[7] = e1.w;
    const float4* xp = (const float4*)(x + (size_t)i * 16);
#pragma unroll
    for (int t = 0; t < 4; t++) {
        float4 v = xp[t];
        in[8 + 4 * t + 0] = v.x; in[8 + 4 * t + 1] = v.y;
        in[8 + 4 * t + 2] = v.z; in[8 + 4 * t + 3] = v.w;
    }
    float acc[8];
#pragma unroll
    for (int j = 0; j < 8; j++) acc[j] = b1[j];
#pragma unroll
    for (int t = 0; t < 24; t++) {
        float xv = in[t];
#pragma unroll
        for (int j = 0; j < 8; j++) acc[j] = fmaf(xv, W1[t * 8 + j], acc[j]);
    }
    half8 h;
#pragma unroll
    for (int j = 0; j < 8; j++) h[j] = (_Float16)fmaxf(acc[j], 0.0f);
    *(half8*)(A + (size_t)i * 32) = h;
    *(half8*)(T01 + (size_t)i * 32) = h;
    *(half8*)(T3 + (size_t)i * 48) = h;
}

template <int Li>
__device__ __forceinline__ void attn_out(const float* xs, const float* qv,
                                         const float* __restrict__ wk, const float* __restrict__ bk,
                                         const float* __restrict__ wv, const float* __restrict__ bv,
                                         float* out) {
    float score[2][Li];
#pragma unroll
    for (int l = 0; l < Li; l++) {
#pragma unroll
        for (int h = 0; h < 2; h++) {
            float sc = 0.f;
#pragma unroll
            for (int dd = 0; dd < 4; dd++) {
                int c = h * 4 + dd;
                sc = fmaf(qv[c], fmaf(xs[l * 8 + c], wk[c], bk[c]), sc);
            }
            score[h][l] = 0.5f * sc;
        }
    }
    float attn[2][Li];
#pragma unroll
    for (int h = 0; h < 2; h++) {
        float m = score[h][0];
#pragma unroll
        for (int l = 1; l < Li; l++) m = fmaxf(m, score[h][l]);
        float ssum = 0.f;
#pragma unroll
        for (int l = 0; l < Li; l++) { attn[h][l] = __expf(score[h][l] - m); ssum += attn[h][l]; }
        float inv = 1.0f / ssum;
#pragma unroll
        for (int l = 0; l < Li; l++) attn[h][l] *= inv;
    }
#pragma unroll
    for (int c = 0; c < 8; c++) {
        int h = c >> 2;
        float o = 0.f;
#pragma unroll
        for (int l = 0; l < Li; l++) o = fmaf(attn[h][l], fmaf(xs[l * 8 + c], wv[c], bv[c]), o);
        out[c] = o;
    }
}

// 8 lanes per dst; virtual slot 0 = self-loop; register acc + shfl_xor reduce.
template <int Li, bool LAST>
__global__ void agg_layer(const int* __restrict__ ssrc, const unsigned int* __restrict__ off,
                          const char* __restrict__ A, char* __restrict__ T01,
                          char* __restrict__ T3, const float* __restrict__ dv,
                          const float* __restrict__ wq, const float* __restrict__ bq,
                          const float* __restrict__ wk, const float* __restrict__ bk,
                          const float* __restrict__ wv, const float* __restrict__ bv,
                          const float* __restrict__ W2, const float* __restrict__ b2,
                          float* __restrict__ out, int n) {
    int tid = blockIdx.x * blockDim.x + threadIdx.x;
    int d = tid >> 3, t = tid & 7;
    if (d >= n) return;
    unsigned int ow = off[d];
    int lo = (int)(ow & 0x3FFFFFu), cnt = (int)(ow >> 22);

    half8 qh;
    if (Li == 1) qh = *(const half8*)(A + (size_t)d * 32);
    else if (Li == 2) qh = *(const half8*)(T01 + (size_t)d * 32 + 16);
    else qh = *(const half8*)(T3 + (size_t)d * 48 + 32);
    float qv[8];
#pragma unroll
    for (int c = 0; c < 8; c++) qv[c] = fmaf((float)qh[c], wq[c], bq[c]);

    float acc[8];
#pragma unroll
    for (int c = 0; c < 8; c++) acc[c] = 0.f;

    for (int j = t; j < cnt + 1; j += 8) {
        int s = (j == 0) ? d : __builtin_nontemporal_load(&ssrc[lo + j - 1]);
        float xs[8 * Li];
        float ns;
        if (Li == 1) {
            const char* ab = A + (size_t)s * 32;
            half8 h = *(const half8*)ab;
#pragma unroll
            for (int c = 0; c < 8; c++) xs[c] = (float)h[c];
            ns = *(const float*)(ab + 16);
        } else if (Li == 2) {
            const char* ub = T01 + (size_t)s * 32;
            half8 h0 = *(const half8*)ub;
            half8 h1 = *(const half8*)(ub + 16);
#pragma unroll
            for (int c = 0; c < 8; c++) { xs[c] = (float)h0[c]; xs[8 + c] = (float)h1[c]; }
            ns = dv[s];
        } else {
            const char* ub = T3 + (size_t)s * 48;
#pragma unroll
            for (int l = 0; l < 3; l++) {
                half8 h = *(const half8*)(ub + l * 16);
#pragma unroll
                for (int c = 0; c < 8; c++) xs[l * 8 + c] = (float)h[c];
            }
            ns = dv[s];
        }
        float o[8];
        attn_out<Li>(xs, qv, wk, bk, wv, bv, o);
#pragma unroll
        for (int c = 0; c < 8; c++) acc[c] = fmaf(o[c], ns, acc[c]);
    }
#pragma unroll
    for (int m = 1; m < 8; m <<= 1) {
#pragma unroll
        for (int c = 0; c < 8; c++) acc[c] += __shfl_xor(acc[c], m);
    }
    float nd = (Li == 1) ? *(const float*)(A + (size_t)d * 32 + 16) : dv[d];
    if (!LAST) {
        float h = fmaxf(acc[t] * nd, 0.f);
        _Float16 hh = (_Float16)h;
        if (Li == 1) {
            *(_Float16*)(T01 + (size_t)d * 32 + 16 + 2 * t) = hh;   // h1 -> T01 only
        } else {
            // T3 gets h1 (this layer's q row, in registers) + h2
            *(_Float16*)(T3 + (size_t)d * 48 + 16 + 2 * t) = qh[t];
            *(_Float16*)(T3 + (size_t)d * 48 + 32 + 2 * t) = hh;
        }
    } else if (t == 0) {
        float z0 = b2[0], z1 = b2[1];
#pragma unroll
        for (int c = 0; c < 8; c++) {
            float h = fmaxf(acc[c] * nd, 0.f);
            z0 = fmaf(h, W2[c * 2 + 0], z0);
            z1 = fmaf(h, W2[c * 2 + 1], z1);
        }
        float m = fmaxf(z0, z1);
        float lse = m + logf(__expf(z0 - m) + __expf(z1 - m));
        ((float2*)out)[d] = make_float2(z0 - lse, z1 - lse);
    }
}

extern "C" void kernel_launch(void* const* d_in, const int* in_sizes, int n_in,
                              void* d_out, int out_size, void* d_ws, size_t ws_size,
                              hipStream_t stream) {
    const float* x    = (const float*)d_in[0];
    const int*   nidx = (const int*)d_in[1];
    const int*   eidx = (const int*)d_in[3];
    const float* emb  = (const float*)d_in[5];
    const float* W1   = (const float*)d_in[6];
    const float* b1   = (const float*)d_in[7];
    const float* Wq   = (const float*)d_in[8];
    const float* bq   = (const float*)d_in[9];
    const float* Wk   = (const float*)d_in[10];
    const float* bk   = (const float*)d_in[11];
    const float* Wv   = (const float*)d_in[12];
    const float* bv   = (const float*)d_in[13];
    const float* W2   = (const float*)d_in[14];
    const float* b2   = (const float*)d_in[15];
    float* out = (float*)d_out;

    const int n = in_sizes[0] / 16;            // 100000
    const int E = in_sizes[3] / 2;             // 3200000
    const int NS = (n + SBN - 1) / SBN;        // 391
    const int NBLK = (E + CH - 1) / CH;        // 782

    char* wsp = (char*)d_ws;
    char*  A     = wsp;                      wsp += (size_t)n * 32;
    char*  T01   = wsp;                      wsp += (size_t)n * 32;
    char*  T3    = wsp;                      wsp += (size_t)n * 48;
    float* dv    = (float*)wsp;              wsp += (size_t)n * 4;
    int*   ebuf  = (int*)wsp;                wsp += (size_t)NS * CAP * 4;
    unsigned int* off = (unsigned int*)wsp;  wsp += (size_t)n * 4;
    int*   gcnt  = (int*)wsp;                wsp += (size_t)NS * 4;

    dim3 blk(256);
    dim3 gn((n + 255) / 256);
    dim3 ga(((size_t)n * 8 + 255) / 256);

    (void)hipMemsetAsync(gcnt, 0, (size_t)NS * 4, stream);
    phaseAC<<<NBLK, blk, 0, stream>>>(eidx, gcnt, ebuf, E, NS);
    super_csr<<<NS, blk, 0, stream>>>(ebuf, gcnt, off, A, dv, NS, n);
    node_init<<<gn, blk, 0, stream>>>(x, nidx, emb, W1, b1, A, T01, T3, n);

    agg_layer<1, false><<<ga, blk, 0, stream>>>(ebuf, off, A, T01, T3, dv,
        Wq, bq, Wk, bk, Wv, bv, W2, b2, out, n);
    agg_layer<2, false><<<ga, blk, 0, stream>>>(ebuf, off, A, T01, T3, dv,
        Wq + 8, bq + 8, Wk + 8, bk + 8, Wv + 8, bv + 8, W2, b2, out, n);
    agg_layer<3, true><<<ga, blk, 0, stream>>>(ebuf, off, A, T01, T3, dv,
        Wq + 16, bq + 16, Wk + 16, bk + 16, Wv + 16, bv + 16, W2, b2, out, n);
}

// Round 13
// 276.798 us; speedup vs baseline: 1.4507x; 1.1543x over previous
//
#include <hip/hip_runtime.h>
#include <math.h>

// DNA-GNN: N=100000, E=3200000, C=8, HEADS=2, d_head=4, 3 layers.
// glin GROUPS=8, cin=cout=1 => per-channel scale+bias.
//
// Round 13: r8 table layout (dinv co-located in the gather line) + 4-wide
// memory-level parallelism in agg.
//   A (N,32B): [8 fp16 h0 | f32 dinv]        3.2MB -> layer-1 gathers
//   U (N,64B): [h0|h1|h2 fp16 | f32 dinv@48] 6.4MB -> layer-2/3 gathers
//   agg: 8 lanes/dst, each lane owns a CONTIGUOUS slot chunk, processed in
//   batches of 4: 4 src loads (1 line) -> 4 independent row gathers in
//   flight -> 4 attn computes. Attacks the latency-bound serial chain
//   (r8: 1 gather in flight, 1.9 TB/s, VALUBusy 36%).
//   nt loads only in build kernels (r12 showed nt in agg = +9us regression).
// CSR build: phaseAC single-pass super sort (CH=4096) + super_csr.

#define SBB   8
#define SBN   256
#define CH    4096
#define CAP   9216

typedef _Float16 half8 __attribute__((ext_vector_type(8)));
typedef int int4v __attribute__((ext_vector_type(4)));

__global__ void __launch_bounds__(256) phaseAC(const int* __restrict__ eidx,
                                               int* __restrict__ gcnt,
                                               int* __restrict__ ebuf,
                                               int E, int NS) {
    __shared__ int sorted_[CH];            // 16KB
    __shared__ unsigned short karr[CH];    // 8KB
    __shared__ int cntS[512];
    __shared__ int lofs[512];
    __shared__ int wbase[512];
    __shared__ int sA[512], sB[512];
    int t = threadIdx.x, b = blockIdx.x;
    int base = b * CH;
    int nEdge = E - base; if (nEdge > CH) nEdge = CH;

    for (int i = t; i < 512; i += 256) cntS[i] = 0;
    __syncthreads();

    int w[16]; short kk[16];
#pragma unroll
    for (int it = 0; it < 4; it++) {
        int e0 = base + (it * 256 + t) * 4;
        if (e0 + 3 < E) {
            int4v s4 = __builtin_nontemporal_load((const int4v*)(eidx + e0));
            int4v d4 = __builtin_nontemporal_load((const int4v*)(eidx + E + e0));
#pragma unroll
            for (int j = 0; j < 4; j++) {
                int idx = it * 4 + j;
                w[idx] = s4[j] | ((d4[j] & (SBN - 1)) << 17);
                kk[idx] = (short)(d4[j] >> SBB);
                atomicAdd(&cntS[kk[idx]], 1);
            }
        } else {
#pragma unroll
            for (int j = 0; j < 4; j++) {
                int e = e0 + j, idx = it * 4 + j;
                if (e < E) {
                    int s = eidx[e], d = eidx[E + e];
                    w[idx] = s | ((d & (SBN - 1)) << 17);
                    kk[idx] = (short)(d >> SBB);
                    atomicAdd(&cntS[kk[idx]], 1);
                } else { w[idx] = 0; kk[idx] = 511; }
            }
        }
    }
    __syncthreads();
    sA[t] = cntS[t]; sA[t + 256] = cntS[t + 256];
    __syncthreads();
    int* sp = sA; int* dp = sB;
    for (int o = 1; o < 512; o <<= 1) {
#pragma unroll
        for (int h = 0; h < 2; h++) {
            int i = t + h * 256;
            int v = sp[i];
            if (i >= o) v += sp[i - o];
            dp[i] = v;
        }
        __syncthreads();
        int* tmp = sp; sp = dp; dp = tmp;
    }
    for (int i = t; i < 512; i += 256) {
        int excl = sp[i] - cntS[i];
        lofs[i] = excl;
        if (i < NS && cntS[i] > 0) {
            int g = atomicAdd(&gcnt[i], cntS[i]);
            wbase[i] = i * CAP + g - excl;
        }
    }
    __syncthreads();
#pragma unroll
    for (int idx = 0; idx < 16; idx++) {
        if (kk[idx] != 511) {
            int p = atomicAdd(&lofs[kk[idx]], 1);
            sorted_[p] = w[idx];
            karr[p] = (unsigned short)kk[idx];
        }
    }
    __syncthreads();
    for (int i = t; i < nEdge; i += 256)
        ebuf[wbase[karr[i]] + i] = sorted_[i];     // plain store: L2-absorbed
}

// One WG per super: stage region, count 256 dls, scan, dl-sort in place;
// emit packed off (pos | deg<<22), dinv -> A@16 and U@48.
__global__ void super_csr(int* __restrict__ ebuf, const int* __restrict__ gcnt,
                          unsigned int* __restrict__ off, char* __restrict__ A,
                          char* __restrict__ U, int NS, int n) {
    __shared__ int seg[CAP];
    __shared__ int cnt[SBN];
    __shared__ int fillp[SBN];
    __shared__ int sd[256];
    int t = threadIdx.x, k = blockIdx.x;
    cnt[t] = 0;
    int start = k * CAP;
    int len = gcnt[k];
    __syncthreads();
    for (int i = t; i < len; i += 256) {
        int w = __builtin_nontemporal_load(&ebuf[start + i]);
        seg[i] = w;
        atomicAdd(&cnt[w >> 17], 1);
    }
    __syncthreads();
    int v = cnt[t];
    sd[t] = v; __syncthreads();
    for (int o = 1; o < 256; o <<= 1) {
        int u = 0; if (t >= o) u = sd[t - o];
        __syncthreads(); sd[t] += u; __syncthreads();
    }
    int excl = sd[t] - v;
    fillp[t] = excl;
    int d = (k << SBB) + t;
    if (d < n) {
        off[d] = (unsigned int)(start + excl) | ((unsigned int)v << 22);
        float dvv = rsqrtf((float)(v + 1));   // +1 self-loop
        *(float*)(A + (size_t)d * 32 + 16) = dvv;
        *(float*)(U + (size_t)d * 64 + 48) = dvv;
    }
    __syncthreads();
    for (int i = t; i < len; i += 256) {
        int w = seg[i];
        int pos = atomicAdd(&fillp[w >> 17], 1);
        ebuf[start + pos] = w & 131071;            // plain store: L2-absorbed
    }
}

// h0 = relu([emb[nidx], x] @ W1 + b1) -> A and U ch0..7
__global__ void node_init(const float* __restrict__ x, const int* __restrict__ nidx,
                          const float* __restrict__ emb, const float* __restrict__ W1,
                          const float* __restrict__ b1, char* __restrict__ A,
                          char* __restrict__ U, int n) {
    int i = blockIdx.x * blockDim.x + threadIdx.x;
    if (i >= n) return;
    float in[24];
    int ni = nidx[i];
    const float4* ep = (const float4*)(emb + (size_t)ni * 8);
    float4 e0 = ep[0], e1 = ep[1];
    in[0] = e0.x; in[1] = e0.y; in[2] = e0.z; in[3] = e0.w;
    in[4] = e1.x; in[5] = e1.y; in[6] = e1.z; in[7] = e1.w;
    const float4* xp = (const float4*)(x + (size_t)i * 16);
#pragma unroll
    for (int t = 0; t < 4; t++) {
        float4 v = xp[t];
        in[8 + 4 * t + 0] = v.x; in[8 + 4 * t + 1] = v.y;
        in[8 + 4 * t + 2] = v.z; in[8 + 4 * t + 3] = v.w;
    }
    float acc[8];
#pragma unroll
    for (int j = 0; j < 8; j++) acc[j] = b1[j];
#pragma unroll
    for (int t = 0; t < 24; t++) {
        float xv = in[t];
#pragma unroll
        for (int j = 0; j < 8; j++) acc[j] = fmaf(xv, W1[t * 8 + j], acc[j]);
    }
    half8 h;
#pragma unroll
    for (int j = 0; j < 8; j++) h[j] = (_Float16)fmaxf(acc[j], 0.0f);
    *(half8*)(A + (size_t)i * 32) = h;
    *(half8*)(U + (size_t)i * 64) = h;
}

template <int Li>
__device__ __forceinline__ void attn_out(const float* xs, const float* qv,
                                         const float* __restrict__ wk, const float* __restrict__ bk,
                                         const float* __restrict__ wv, const float* __restrict__ bv,
                                         float* out) {
    float score[2][Li];
#pragma unroll
    for (int l = 0; l < Li; l++) {
#pragma unroll
        for (int h = 0; h < 2; h++) {
            float sc = 0.f;
#pragma unroll
            for (int dd = 0; dd < 4; dd++) {
                int c = h * 4 + dd;
                sc = fmaf(qv[c], fmaf(xs[l * 8 + c], wk[c], bk[c]), sc);
            }
            score[h][l] = 0.5f * sc;
        }
    }
    float attn[2][Li];
#pragma unroll
    for (int h = 0; h < 2; h++) {
        float m = score[h][0];
#pragma unroll
        for (int l = 1; l < Li; l++) m = fmaxf(m, score[h][l]);
        float ssum = 0.f;
#pragma unroll
        for (int l = 0; l < Li; l++) { attn[h][l] = __expf(score[h][l] - m); ssum += attn[h][l]; }
        float inv = 1.0f / ssum;
#pragma unroll
        for (int l = 0; l < Li; l++) attn[h][l] *= inv;
    }
#pragma unroll
    for (int c = 0; c < 8; c++) {
        int h = c >> 2;
        float o = 0.f;
#pragma unroll
        for (int l = 0; l < Li; l++) o = fmaf(attn[h][l], fmaf(xs[l * 8 + c], wv[c], bv[c]), o);
        out[c] = o;
    }
}

// 8 lanes per dst; lane owns contiguous chunk of slots (slot 0 = virtual
// self-loop); batches of 4 slots -> 4 independent row gathers in flight.
template <int Li, bool LAST>
__global__ void agg_layer(const int* __restrict__ ssrc, const unsigned int* __restrict__ off,
                          const char* __restrict__ A, char* __restrict__ U,
                          const float* __restrict__ wq, const float* __restrict__ bq,
                          const float* __restrict__ wk, const float* __restrict__ bk,
                          const float* __restrict__ wv, const float* __restrict__ bv,
                          const float* __restrict__ W2, const float* __restrict__ b2,
                          float* __restrict__ out, int n) {
    int tid = blockIdx.x * blockDim.x + threadIdx.x;
    int d = tid >> 3, t = tid & 7;
    if (d >= n) return;
    unsigned int ow = off[d];
    int lo = (int)(ow & 0x3FFFFFu), cnt = (int)(ow >> 22);

    half8 qh;
    if (Li == 1) qh = *(const half8*)(A + (size_t)d * 32);
    else if (Li == 2) qh = *(const half8*)(U + (size_t)d * 64 + 16);
    else qh = *(const half8*)(U + (size_t)d * 64 + 32);
    float qv[8];
#pragma unroll
    for (int c = 0; c < 8; c++) qv[c] = fmaf((float)qh[c], wq[c], bq[c]);

    float acc[8];
#pragma unroll
    for (int c = 0; c < 8; c++) acc[c] = 0.f;

    int total = cnt + 1;                 // + virtual self slot 0
    int g = (total + 7) >> 3;            // slots per lane (contiguous chunk)
    int j0 = t * g;
    int j1 = j0 + g; if (j1 > total) j1 = total;

    for (int j = j0; j < j1; j += 4) {
        int m = j1 - j; if (m > 4) m = 4;
        int sidx[4];
#pragma unroll
        for (int u = 0; u < 4; u++) {
            int idx = j + u;
            sidx[u] = (u < m) ? ((idx == 0) ? d : ssrc[lo + idx - 1]) : d;
        }
        half8 r[4][Li]; float nsv[4];
#pragma unroll
        for (int u = 0; u < 4; u++) {
            if (u < m) {
                if (Li == 1) {
                    const char* p = A + (size_t)sidx[u] * 32;
                    r[u][0] = *(const half8*)p;
                    nsv[u] = *(const float*)(p + 16);
                } else {
                    const char* p = U + (size_t)sidx[u] * 64;
#pragma unroll
                    for (int l = 0; l < Li; l++) r[u][l] = *(const half8*)(p + l * 16);
                    nsv[u] = *(const float*)(p + 48);
                }
            }
        }
#pragma unroll
        for (int u = 0; u < 4; u++) {
            if (u < m) {
                float xs[8 * Li];
#pragma unroll
                for (int l = 0; l < Li; l++)
#pragma unroll
                    for (int c = 0; c < 8; c++) xs[l * 8 + c] = (float)r[u][l][c];
                float o[8];
                attn_out<Li>(xs, qv, wk, bk, wv, bv, o);
#pragma unroll
                for (int c = 0; c < 8; c++) acc[c] = fmaf(o[c], nsv[u], acc[c]);
            }
        }
    }
#pragma unroll
    for (int m2 = 1; m2 < 8; m2 <<= 1) {
#pragma unroll
        for (int c = 0; c < 8; c++) acc[c] += __shfl_xor(acc[c], m2);
    }
    float nd = (Li == 1) ? *(const float*)(A + (size_t)d * 32 + 16)
                         : *(const float*)(U + (size_t)d * 64 + 48);
    if (!LAST) {
        float h = fmaxf(acc[t] * nd, 0.f);
        *(_Float16*)(U + (size_t)d * 64 + Li * 16 + 2 * t) = (_Float16)h;
    } else if (t == 0) {
        float z0 = b2[0], z1 = b2[1];
#pragma unroll
        for (int c = 0; c < 8; c++) {
            float h = fmaxf(acc[c] * nd, 0.f);
            z0 = fmaf(h, W2[c * 2 + 0], z0);
            z1 = fmaf(h, W2[c * 2 + 1], z1);
        }
        float m2 = fmaxf(z0, z1);
        float lse = m2 + logf(__expf(z0 - m2) + __expf(z1 - m2));
        ((float2*)out)[d] = make_float2(z0 - lse, z1 - lse);
    }
}

extern "C" void kernel_launch(void* const* d_in, const int* in_sizes, int n_in,
                              void* d_out, int out_size, void* d_ws, size_t ws_size,
                              hipStream_t stream) {
    const float* x    = (const float*)d_in[0];
    const int*   nidx = (const int*)d_in[1];
    const int*   eidx = (const int*)d_in[3];
    const float* emb  = (const float*)d_in[5];
    const float* W1   = (const float*)d_in[6];
    const float* b1   = (const float*)d_in[7];
    const float* Wq   = (const float*)d_in[8];
    const float* bq   = (const float*)d_in[9];
    const float* Wk   = (const float*)d_in[10];
    const float* bk   = (const float*)d_in[11];
    const float* Wv   = (const float*)d_in[12];
    const float* bv   = (const float*)d_in[13];
    const float* W2   = (const float*)d_in[14];
    const float* b2   = (const float*)d_in[15];
    float* out = (float*)d_out;

    const int n = in_sizes[0] / 16;            // 100000
    const int E = in_sizes[3] / 2;             // 3200000
    const int NS = (n + SBN - 1) / SBN;        // 391
    const int NBLK = (E + CH - 1) / CH;        // 782

    char* wsp = (char*)d_ws;
    char*  A     = wsp;                      wsp += (size_t)n * 32;
    char*  U     = wsp;                      wsp += (size_t)n * 64;
    int*   ebuf  = (int*)wsp;                wsp += (size_t)NS * CAP * 4;
    unsigned int* off = (unsigned int*)wsp;  wsp += (size_t)n * 4;
    int*   gcnt  = (int*)wsp;                wsp += (size_t)NS * 4;

    dim3 blk(256);
    dim3 gn((n + 255) / 256);
    dim3 ga(((size_t)n * 8 + 255) / 256);

    (void)hipMemsetAsync(gcnt, 0, (size_t)NS * 4, stream);
    phaseAC<<<NBLK, blk, 0, stream>>>(eidx, gcnt, ebuf, E, NS);
    super_csr<<<NS, blk, 0, stream>>>(ebuf, gcnt, off, A, U, NS, n);
    node_init<<<gn, blk, 0, stream>>>(x, nidx, emb, W1, b1, A, U, n);

    agg_layer<1, false><<<ga, blk, 0, stream>>>(ebuf, off, A, U,
        Wq, bq, Wk, bk, Wv, bv, W2, b2, out, n);
    agg_layer<2, false><<<ga, blk, 0, stream>>>(ebuf, off, A, U,
        Wq + 8, bq + 8, Wk + 8, bk + 8, Wv + 8, bv + 8, W2, b2, out, n);
    agg_layer<3, true><<<ga, blk, 0, stream>>>(ebuf, off, A, U,
        Wq + 16, bq + 16, Wk + 16, bk + 16, Wv + 16, bv + 16, W2, b2, out, n);
}

// Round 14
// 275.636 us; speedup vs baseline: 1.4568x; 1.0042x over previous
//
#include <hip/hip_runtime.h>
#include <math.h>

// DNA-GNN: N=100000, E=3200000, C=8, HEADS=2, d_head=4, 3 layers.
// glin GROUPS=8, cin=cout=1 => per-channel scale+bias.
//
// Round 14: algebraic attention slimming on top of r13.
//   - softmax shift-invariance: bk drops out; qk[c]=0.5*wk[c]*qv[c] per dst.
//   - sum(attn)=1: accumulate T[c]=sum_e ns*(attn-weighted xs), SN=sum_e ns;
//     wv/bv applied once per dst in the epilogue.
//   - Li=1: attn==1 identically -> no scores/exp/q at all; batch=8.
// Tables: A (N,32B: h0 fp16 + f32 dinv) 3.2MB; U (N,64B: h0|h1|h2 + dinv@48).
// CSR build: phaseAC single-pass super sort (CH=4096) + super_csr (as r13).

#define SBB   8
#define SBN   256
#define CH    4096
#define CAP   9216

typedef _Float16 half8 __attribute__((ext_vector_type(8)));
typedef int int4v __attribute__((ext_vector_type(4)));

__global__ void __launch_bounds__(256) phaseAC(const int* __restrict__ eidx,
                                               int* __restrict__ gcnt,
                                               int* __restrict__ ebuf,
                                               int E, int NS) {
    __shared__ int sorted_[CH];
    __shared__ unsigned short karr[CH];
    __shared__ int cntS[512];
    __shared__ int lofs[512];
    __shared__ int wbase[512];
    __shared__ int sA[512], sB[512];
    int t = threadIdx.x, b = blockIdx.x;
    int base = b * CH;
    int nEdge = E - base; if (nEdge > CH) nEdge = CH;

    for (int i = t; i < 512; i += 256) cntS[i] = 0;
    __syncthreads();

    int w[16]; short kk[16];
#pragma unroll
    for (int it = 0; it < 4; it++) {
        int e0 = base + (it * 256 + t) * 4;
        if (e0 + 3 < E) {
            int4v s4 = __builtin_nontemporal_load((const int4v*)(eidx + e0));
            int4v d4 = __builtin_nontemporal_load((const int4v*)(eidx + E + e0));
#pragma unroll
            for (int j = 0; j < 4; j++) {
                int idx = it * 4 + j;
                w[idx] = s4[j] | ((d4[j] & (SBN - 1)) << 17);
                kk[idx] = (short)(d4[j] >> SBB);
                atomicAdd(&cntS[kk[idx]], 1);
            }
        } else {
#pragma unroll
            for (int j = 0; j < 4; j++) {
                int e = e0 + j, idx = it * 4 + j;
                if (e < E) {
                    int s = eidx[e], d = eidx[E + e];
                    w[idx] = s | ((d & (SBN - 1)) << 17);
                    kk[idx] = (short)(d >> SBB);
                    atomicAdd(&cntS[kk[idx]], 1);
                } else { w[idx] = 0; kk[idx] = 511; }
            }
        }
    }
    __syncthreads();
    sA[t] = cntS[t]; sA[t + 256] = cntS[t + 256];
    __syncthreads();
    int* sp = sA; int* dp = sB;
    for (int o = 1; o < 512; o <<= 1) {
#pragma unroll
        for (int h = 0; h < 2; h++) {
            int i = t + h * 256;
            int v = sp[i];
            if (i >= o) v += sp[i - o];
            dp[i] = v;
        }
        __syncthreads();
        int* tmp = sp; sp = dp; dp = tmp;
    }
    for (int i = t; i < 512; i += 256) {
        int excl = sp[i] - cntS[i];
        lofs[i] = excl;
        if (i < NS && cntS[i] > 0) {
            int g = atomicAdd(&gcnt[i], cntS[i]);
            wbase[i] = i * CAP + g - excl;
        }
    }
    __syncthreads();
#pragma unroll
    for (int idx = 0; idx < 16; idx++) {
        if (kk[idx] != 511) {
            int p = atomicAdd(&lofs[kk[idx]], 1);
            sorted_[p] = w[idx];
            karr[p] = (unsigned short)kk[idx];
        }
    }
    __syncthreads();
    for (int i = t; i < nEdge; i += 256)
        ebuf[wbase[karr[i]] + i] = sorted_[i];
}

__global__ void super_csr(int* __restrict__ ebuf, const int* __restrict__ gcnt,
                          unsigned int* __restrict__ off, char* __restrict__ A,
                          char* __restrict__ U, int NS, int n) {
    __shared__ int seg[CAP];
    __shared__ int cnt[SBN];
    __shared__ int fillp[SBN];
    __shared__ int sd[256];
    int t = threadIdx.x, k = blockIdx.x;
    cnt[t] = 0;
    int start = k * CAP;
    int len = gcnt[k];
    __syncthreads();
    for (int i = t; i < len; i += 256) {
        int w = __builtin_nontemporal_load(&ebuf[start + i]);
        seg[i] = w;
        atomicAdd(&cnt[w >> 17], 1);
    }
    __syncthreads();
    int v = cnt[t];
    sd[t] = v; __syncthreads();
    for (int o = 1; o < 256; o <<= 1) {
        int u = 0; if (t >= o) u = sd[t - o];
        __syncthreads(); sd[t] += u; __syncthreads();
    }
    int excl = sd[t] - v;
    fillp[t] = excl;
    int d = (k << SBB) + t;
    if (d < n) {
        off[d] = (unsigned int)(start + excl) | ((unsigned int)v << 22);
        float dvv = rsqrtf((float)(v + 1));   // +1 self-loop
        *(float*)(A + (size_t)d * 32 + 16) = dvv;
        *(float*)(U + (size_t)d * 64 + 48) = dvv;
    }
    __syncthreads();
    for (int i = t; i < len; i += 256) {
        int w = seg[i];
        int pos = atomicAdd(&fillp[w >> 17], 1);
        ebuf[start + pos] = w & 131071;
    }
}

__global__ void node_init(const float* __restrict__ x, const int* __restrict__ nidx,
                          const float* __restrict__ emb, const float* __restrict__ W1,
                          const float* __restrict__ b1, char* __restrict__ A,
                          char* __restrict__ U, int n) {
    int i = blockIdx.x * blockDim.x + threadIdx.x;
    if (i >= n) return;
    float in[24];
    int ni = nidx[i];
    const float4* ep = (const float4*)(emb + (size_t)ni * 8);
    float4 e0 = ep[0], e1 = ep[1];
    in[0] = e0.x; in[1] = e0.y; in[2] = e0.z; in[3] = e0.w;
    in[4] = e1.x; in[5] = e1.y; in[6] = e1.z; in[7] = e1.w;
    const float4* xp = (const float4*)(x + (size_t)i * 16);
#pragma unroll
    for (int t = 0; t < 4; t++) {
        float4 v = xp[t];
        in[8 + 4 * t + 0] = v.x; in[8 + 4 * t + 1] = v.y;
        in[8 + 4 * t + 2] = v.z; in[8 + 4 * t + 3] = v.w;
    }
    float acc[8];
#pragma unroll
    for (int j = 0; j < 8; j++) acc[j] = b1[j];
#pragma unroll
    for (int t = 0; t < 24; t++) {
        float xv = in[t];
#pragma unroll
        for (int j = 0; j < 8; j++) acc[j] = fmaf(xv, W1[t * 8 + j], acc[j]);
    }
    half8 h;
#pragma unroll
    for (int j = 0; j < 8; j++) h[j] = (_Float16)fmaxf(acc[j], 0.0f);
    *(half8*)(A + (size_t)i * 32) = h;
    *(half8*)(U + (size_t)i * 64) = h;
}

// 8 lanes per dst; lane owns a contiguous slot chunk (slot 0 = virtual
// self-loop); batches of B slots -> B independent row gathers in flight.
// Accumulates T[c] = sum_e ns*(attn-weighted xs[c]) and SN = sum_e ns;
// epilogue applies wv/bv once: out = wv*T + bv*SN.
template <int Li, bool LAST>
__global__ void agg_layer(const int* __restrict__ ssrc, const unsigned int* __restrict__ off,
                          const char* __restrict__ A, char* __restrict__ U,
                          const float* __restrict__ wq, const float* __restrict__ bq,
                          const float* __restrict__ wk, const float* __restrict__ bk,
                          const float* __restrict__ wv, const float* __restrict__ bv,
                          const float* __restrict__ W2, const float* __restrict__ b2,
                          float* __restrict__ out, int n) {
    constexpr int B = (Li == 1) ? 8 : 4;
    int tid = blockIdx.x * blockDim.x + threadIdx.x;
    int d = tid >> 3, t = tid & 7;
    if (d >= n) return;
    unsigned int ow = off[d];
    int lo = (int)(ow & 0x3FFFFFu), cnt = (int)(ow >> 22);

    float qk[8];
    if (Li >= 2) {
        half8 qh = (Li == 2) ? *(const half8*)(U + (size_t)d * 64 + 16)
                             : *(const half8*)(U + (size_t)d * 64 + 32);
#pragma unroll
        for (int c = 0; c < 8; c++) {
            float qv = fmaf((float)qh[c], wq[c], bq[c]);
            qk[c] = 0.5f * wk[c] * qv;     // bk drops out of softmax
        }
    }

    float T[8]; float SN = 0.f;
#pragma unroll
    for (int c = 0; c < 8; c++) T[c] = 0.f;

    int total = cnt + 1;
    int g = (total + 7) >> 3;
    int j0 = t * g;
    int j1 = j0 + g; if (j1 > total) j1 = total;

    for (int j = j0; j < j1; j += B) {
        int m = j1 - j; if (m > B) m = B;
        int sidx[B];
#pragma unroll
        for (int u = 0; u < B; u++) {
            int idx = j + u;
            sidx[u] = (u < m) ? ((idx == 0) ? d : ssrc[lo + idx - 1]) : d;
        }
        half8 r[B][Li]; float nsv[B];
#pragma unroll
        for (int u = 0; u < B; u++) {
            if (u < m) {
                if (Li == 1) {
                    const char* p = A + (size_t)sidx[u] * 32;
                    r[u][0] = *(const half8*)p;
                    nsv[u] = *(const float*)(p + 16);
                } else {
                    const char* p = U + (size_t)sidx[u] * 64;
#pragma unroll
                    for (int l = 0; l < Li; l++) r[u][l] = *(const half8*)(p + l * 16);
                    nsv[u] = *(const float*)(p + 48);
                }
            }
        }
#pragma unroll
        for (int u = 0; u < B; u++) {
            if (u < m) {
                float xs[8 * Li];
#pragma unroll
                for (int l = 0; l < Li; l++)
#pragma unroll
                    for (int c = 0; c < 8; c++) xs[l * 8 + c] = (float)r[u][l][c];
                float ns = nsv[u];
                if (Li == 1) {
                    // attn == 1: plain ns-weighted sum
#pragma unroll
                    for (int c = 0; c < 8; c++) T[c] = fmaf(ns, xs[c], T[c]);
                    SN += ns;
                } else {
                    float score[2][Li];
#pragma unroll
                    for (int l = 0; l < Li; l++) {
#pragma unroll
                        for (int h = 0; h < 2; h++) {
                            float sc = 0.f;
#pragma unroll
                            for (int dd = 0; dd < 4; dd++) {
                                int c = h * 4 + dd;
                                sc = fmaf(qk[c], xs[l * 8 + c], sc);
                            }
                            score[h][l] = sc;
                        }
                    }
                    float e[2][Li], nsh[2];
#pragma unroll
                    for (int h = 0; h < 2; h++) {
                        float mx = score[h][0];
#pragma unroll
                        for (int l = 1; l < Li; l++) mx = fmaxf(mx, score[h][l]);
                        float ssum = 0.f;
#pragma unroll
                        for (int l = 0; l < Li; l++) { e[h][l] = __expf(score[h][l] - mx); ssum += e[h][l]; }
                        nsh[h] = ns / ssum;
                    }
#pragma unroll
                    for (int c = 0; c < 8; c++) {
                        int h = c >> 2;
                        float P = 0.f;
#pragma unroll
                        for (int l = 0; l < Li; l++) P = fmaf(e[h][l], xs[l * 8 + c], P);
                        T[c] = fmaf(nsh[h], P, T[c]);
                    }
                    SN += ns;
                }
            }
        }
    }
#pragma unroll
    for (int m2 = 1; m2 < 8; m2 <<= 1) {
#pragma unroll
        for (int c = 0; c < 8; c++) T[c] += __shfl_xor(T[c], m2);
        SN += __shfl_xor(SN, m2);
    }
    float nd = (Li == 1) ? *(const float*)(A + (size_t)d * 32 + 16)
                         : *(const float*)(U + (size_t)d * 64 + 48);
    if (!LAST) {
        float acc = fmaf(wv[t], T[t], bv[t] * SN);
        float h = fmaxf(acc * nd, 0.f);
        *(_Float16*)(U + (size_t)d * 64 + Li * 16 + 2 * t) = (_Float16)h;
    } else if (t == 0) {
        float z0 = b2[0], z1 = b2[1];
#pragma unroll
        for (int c = 0; c < 8; c++) {
            float acc = fmaf(wv[c], T[c], bv[c] * SN);
            float h = fmaxf(acc * nd, 0.f);
            z0 = fmaf(h, W2[c * 2 + 0], z0);
            z1 = fmaf(h, W2[c * 2 + 1], z1);
        }
        float m2 = fmaxf(z0, z1);
        float lse = m2 + logf(__expf(z0 - m2) + __expf(z1 - m2));
        ((float2*)out)[d] = make_float2(z0 - lse, z1 - lse);
    }
}

extern "C" void kernel_launch(void* const* d_in, const int* in_sizes, int n_in,
                              void* d_out, int out_size, void* d_ws, size_t ws_size,
                              hipStream_t stream) {
    const float* x    = (const float*)d_in[0];
    const int*   nidx = (const int*)d_in[1];
    const int*   eidx = (const int*)d_in[3];
    const float* emb  = (const float*)d_in[5];
    const float* W1   = (const float*)d_in[6];
    const float* b1   = (const float*)d_in[7];
    const float* Wq   = (const float*)d_in[8];
    const float* bq   = (const float*)d_in[9];
    const float* Wk   = (const float*)d_in[10];
    const float* bk   = (const float*)d_in[11];
    const float* Wv   = (const float*)d_in[12];
    const float* bv   = (const float*)d_in[13];
    const float* W2   = (const float*)d_in[14];
    const float* b2   = (const float*)d_in[15];
    float* out = (float*)d_out;

    const int n = in_sizes[0] / 16;            // 100000
    const int E = in_sizes[3] / 2;             // 3200000
    const int NS = (n + SBN - 1) / SBN;        // 391
    const int NBLK = (E + CH - 1) / CH;        // 782

    char* wsp = (char*)d_ws;
    char*  A     = wsp;                      wsp += (size_t)n * 32;
    char*  U     = wsp;                      wsp += (size_t)n * 64;
    int*   ebuf  = (int*)wsp;                wsp += (size_t)NS * CAP * 4;
    unsigned int* off = (unsigned int*)wsp;  wsp += (size_t)n * 4;
    int*   gcnt  = (int*)wsp;                wsp += (size_t)NS * 4;

    dim3 blk(256);
    dim3 gn((n + 255) / 256);
    dim3 ga(((size_t)n * 8 + 255) / 256);

    (void)hipMemsetAsync(gcnt, 0, (size_t)NS * 4, stream);
    phaseAC<<<NBLK, blk, 0, stream>>>(eidx, gcnt, ebuf, E, NS);
    super_csr<<<NS, blk, 0, stream>>>(ebuf, gcnt, off, A, U, NS, n);
    node_init<<<gn, blk, 0, stream>>>(x, nidx, emb, W1, b1, A, U, n);

    agg_layer<1, false><<<ga, blk, 0, stream>>>(ebuf, off, A, U,
        Wq, bq, Wk, bk, Wv, bv, W2, b2, out, n);
    agg_layer<2, false><<<ga, blk, 0, stream>>>(ebuf, off, A, U,
        Wq + 8, bq + 8, Wk + 8, bk + 8, Wv + 8, bv + 8, W2, b2, out, n);
    agg_layer<3, true><<<ga, blk, 0, stream>>>(ebuf, off, A, U,
        Wq + 16, bq + 16, Wk + 16, bk + 16, Wv + 16, bv + 16, W2, b2, out, n);
}

// Round 15
// 272.588 us; speedup vs baseline: 1.4731x; 1.0112x over previous
//
#include <hip/hip_runtime.h>
#include <math.h>

// DNA-GNN: N=100000, E=3200000, C=8, HEADS=2, d_head=4, 3 layers.
// glin GROUPS=8, cin=cout=1 => per-channel scale+bias.
//
// Round 15: deeper gather pipelining (latency-bound agg).
//   - batch width B: Li=1 -> 8, Li=2 -> 8 (was 4), Li=3 -> 5 (was 4).
//   - gcnt zeroing folded into node_init (launched first); memset dispatch gone.
//   - r14 algebra kept: bk dropped (softmax shift-invariance), wv/bv applied
//     once per dst (sum attn = 1), Li=1 attention-free.
// Tables: A (N,32B: h0 fp16 + f32 dinv) 3.2MB; U (N,64B: h0|h1|h2 + dinv@48).
// CSR build: phaseAC single-pass super sort (CH=4096) + super_csr.

#define SBB   8
#define SBN   256
#define CH    4096
#define CAP   9216

typedef _Float16 half8 __attribute__((ext_vector_type(8)));
typedef int int4v __attribute__((ext_vector_type(4)));

__global__ void __launch_bounds__(256) phaseAC(const int* __restrict__ eidx,
                                               int* __restrict__ gcnt,
                                               int* __restrict__ ebuf,
                                               int E, int NS) {
    __shared__ int sorted_[CH];
    __shared__ unsigned short karr[CH];
    __shared__ int cntS[512];
    __shared__ int lofs[512];
    __shared__ int wbase[512];
    __shared__ int sA[512], sB[512];
    int t = threadIdx.x, b = blockIdx.x;
    int base = b * CH;
    int nEdge = E - base; if (nEdge > CH) nEdge = CH;

    for (int i = t; i < 512; i += 256) cntS[i] = 0;
    __syncthreads();

    int w[16]; short kk[16];
#pragma unroll
    for (int it = 0; it < 4; it++) {
        int e0 = base + (it * 256 + t) * 4;
        if (e0 + 3 < E) {
            int4v s4 = __builtin_nontemporal_load((const int4v*)(eidx + e0));
            int4v d4 = __builtin_nontemporal_load((const int4v*)(eidx + E + e0));
#pragma unroll
            for (int j = 0; j < 4; j++) {
                int idx = it * 4 + j;
                w[idx] = s4[j] | ((d4[j] & (SBN - 1)) << 17);
                kk[idx] = (short)(d4[j] >> SBB);
                atomicAdd(&cntS[kk[idx]], 1);
            }
        } else {
#pragma unroll
            for (int j = 0; j < 4; j++) {
                int e = e0 + j, idx = it * 4 + j;
                if (e < E) {
                    int s = eidx[e], d = eidx[E + e];
                    w[idx] = s | ((d & (SBN - 1)) << 17);
                    kk[idx] = (short)(d >> SBB);
                    atomicAdd(&cntS[kk[idx]], 1);
                } else { w[idx] = 0; kk[idx] = 511; }
            }
        }
    }
    __syncthreads();
    sA[t] = cntS[t]; sA[t + 256] = cntS[t + 256];
    __syncthreads();
    int* sp = sA; int* dp = sB;
    for (int o = 1; o < 512; o <<= 1) {
#pragma unroll
        for (int h = 0; h < 2; h++) {
            int i = t + h * 256;
            int v = sp[i];
            if (i >= o) v += sp[i - o];
            dp[i] = v;
        }
        __syncthreads();
        int* tmp = sp; sp = dp; dp = tmp;
    }
    for (int i = t; i < 512; i += 256) {
        int excl = sp[i] - cntS[i];
        lofs[i] = excl;
        if (i < NS && cntS[i] > 0) {
            int g = atomicAdd(&gcnt[i], cntS[i]);
            wbase[i] = i * CAP + g - excl;
        }
    }
    __syncthreads();
#pragma unroll
    for (int idx = 0; idx < 16; idx++) {
        if (kk[idx] != 511) {
            int p = atomicAdd(&lofs[kk[idx]], 1);
            sorted_[p] = w[idx];
            karr[p] = (unsigned short)kk[idx];
        }
    }
    __syncthreads();
    for (int i = t; i < nEdge; i += 256)
        ebuf[wbase[karr[i]] + i] = sorted_[i];
}

__global__ void super_csr(int* __restrict__ ebuf, const int* __restrict__ gcnt,
                          unsigned int* __restrict__ off, char* __restrict__ A,
                          char* __restrict__ U, int NS, int n) {
    __shared__ int seg[CAP];
    __shared__ int cnt[SBN];
    __shared__ int fillp[SBN];
    __shared__ int sd[256];
    int t = threadIdx.x, k = blockIdx.x;
    cnt[t] = 0;
    int start = k * CAP;
    int len = gcnt[k];
    __syncthreads();
    for (int i = t; i < len; i += 256) {
        int w = __builtin_nontemporal_load(&ebuf[start + i]);
        seg[i] = w;
        atomicAdd(&cnt[w >> 17], 1);
    }
    __syncthreads();
    int v = cnt[t];
    sd[t] = v; __syncthreads();
    for (int o = 1; o < 256; o <<= 1) {
        int u = 0; if (t >= o) u = sd[t - o];
        __syncthreads(); sd[t] += u; __syncthreads();
    }
    int excl = sd[t] - v;
    fillp[t] = excl;
    int d = (k << SBB) + t;
    if (d < n) {
        off[d] = (unsigned int)(start + excl) | ((unsigned int)v << 22);
        float dvv = rsqrtf((float)(v + 1));   // +1 self-loop
        *(float*)(A + (size_t)d * 32 + 16) = dvv;
        *(float*)(U + (size_t)d * 64 + 48) = dvv;
    }
    __syncthreads();
    for (int i = t; i < len; i += 256) {
        int w = seg[i];
        int pos = atomicAdd(&fillp[w >> 17], 1);
        ebuf[start + pos] = w & 131071;
    }
}

// h0 = relu([emb[nidx], x] @ W1 + b1) -> A and U ch0..7; also zeroes gcnt.
__global__ void node_init(const float* __restrict__ x, const int* __restrict__ nidx,
                          const float* __restrict__ emb, const float* __restrict__ W1,
                          const float* __restrict__ b1, char* __restrict__ A,
                          char* __restrict__ U, int* __restrict__ gcnt,
                          int NS, int n) {
    int i = blockIdx.x * blockDim.x + threadIdx.x;
    if (i < NS) gcnt[i] = 0;
    if (i >= n) return;
    float in[24];
    int ni = nidx[i];
    const float4* ep = (const float4*)(emb + (size_t)ni * 8);
    float4 e0 = ep[0], e1 = ep[1];
    in[0] = e0.x; in[1] = e0.y; in[2] = e0.z; in[3] = e0.w;
    in[4] = e1.x; in[5] = e1.y; in[6] = e1.z; in[7] = e1.w;
    const float4* xp = (const float4*)(x + (size_t)i * 16);
#pragma unroll
    for (int t = 0; t < 4; t++) {
        float4 v = xp[t];
        in[8 + 4 * t + 0] = v.x; in[8 + 4 * t + 1] = v.y;
        in[8 + 4 * t + 2] = v.z; in[8 + 4 * t + 3] = v.w;
    }
    float acc[8];
#pragma unroll
    for (int j = 0; j < 8; j++) acc[j] = b1[j];
#pragma unroll
    for (int t = 0; t < 24; t++) {
        float xv = in[t];
#pragma unroll
        for (int j = 0; j < 8; j++) acc[j] = fmaf(xv, W1[t * 8 + j], acc[j]);
    }
    half8 h;
#pragma unroll
    for (int j = 0; j < 8; j++) h[j] = (_Float16)fmaxf(acc[j], 0.0f);
    *(half8*)(A + (size_t)i * 32) = h;
    *(half8*)(U + (size_t)i * 64) = h;
}

// 8 lanes per dst; lane owns a contiguous slot chunk (slot 0 = virtual
// self-loop); batches of B slots -> B independent row gathers in flight.
// T[c] = sum_e ns*(attn-weighted xs[c]), SN = sum_e ns; wv/bv in epilogue.
template <int Li, bool LAST>
__global__ void agg_layer(const int* __restrict__ ssrc, const unsigned int* __restrict__ off,
                          const char* __restrict__ A, char* __restrict__ U,
                          const float* __restrict__ wq, const float* __restrict__ bq,
                          const float* __restrict__ wk, const float* __restrict__ bk,
                          const float* __restrict__ wv, const float* __restrict__ bv,
                          const float* __restrict__ W2, const float* __restrict__ b2,
                          float* __restrict__ out, int n) {
    constexpr int B = (Li == 3) ? 5 : 8;
    int tid = blockIdx.x * blockDim.x + threadIdx.x;
    int d = tid >> 3, t = tid & 7;
    if (d >= n) return;
    unsigned int ow = off[d];
    int lo = (int)(ow & 0x3FFFFFu), cnt = (int)(ow >> 22);

    float qk[8];
    if (Li >= 2) {
        half8 qh = (Li == 2) ? *(const half8*)(U + (size_t)d * 64 + 16)
                             : *(const half8*)(U + (size_t)d * 64 + 32);
#pragma unroll
        for (int c = 0; c < 8; c++) {
            float qv = fmaf((float)qh[c], wq[c], bq[c]);
            qk[c] = 0.5f * wk[c] * qv;     // bk drops out of softmax
        }
    }

    float T[8]; float SN = 0.f;
#pragma unroll
    for (int c = 0; c < 8; c++) T[c] = 0.f;

    int total = cnt + 1;
    int g = (total + 7) >> 3;
    int j0 = t * g;
    int j1 = j0 + g; if (j1 > total) j1 = total;

    for (int j = j0; j < j1; j += B) {
        int m = j1 - j; if (m > B) m = B;
        int sidx[B];
#pragma unroll
        for (int u = 0; u < B; u++) {
            int idx = j + u;
            sidx[u] = (u < m) ? ((idx == 0) ? d : ssrc[lo + idx - 1]) : d;
        }
        half8 r[B][Li]; float nsv[B];
#pragma unroll
        for (int u = 0; u < B; u++) {
            if (u < m) {
                if (Li == 1) {
                    const char* p = A + (size_t)sidx[u] * 32;
                    r[u][0] = *(const half8*)p;
                    nsv[u] = *(const float*)(p + 16);
                } else {
                    const char* p = U + (size_t)sidx[u] * 64;
#pragma unroll
                    for (int l = 0; l < Li; l++) r[u][l] = *(const half8*)(p + l * 16);
                    nsv[u] = *(const float*)(p + 48);
                }
            }
        }
#pragma unroll
        for (int u = 0; u < B; u++) {
            if (u < m) {
                float xs[8 * Li];
#pragma unroll
                for (int l = 0; l < Li; l++)
#pragma unroll
                    for (int c = 0; c < 8; c++) xs[l * 8 + c] = (float)r[u][l][c];
                float ns = nsv[u];
                if (Li == 1) {
#pragma unroll
                    for (int c = 0; c < 8; c++) T[c] = fmaf(ns, xs[c], T[c]);
                    SN += ns;
                } else {
                    float score[2][Li];
#pragma unroll
                    for (int l = 0; l < Li; l++) {
#pragma unroll
                        for (int h = 0; h < 2; h++) {
                            float sc = 0.f;
#pragma unroll
                            for (int dd = 0; dd < 4; dd++) {
                                int c = h * 4 + dd;
                                sc = fmaf(qk[c], xs[l * 8 + c], sc);
                            }
                            score[h][l] = sc;
                        }
                    }
                    float e[2][Li], nsh[2];
#pragma unroll
                    for (int h = 0; h < 2; h++) {
                        float mx = score[h][0];
#pragma unroll
                        for (int l = 1; l < Li; l++) mx = fmaxf(mx, score[h][l]);
                        float ssum = 0.f;
#pragma unroll
                        for (int l = 0; l < Li; l++) { e[h][l] = __expf(score[h][l] - mx); ssum += e[h][l]; }
                        nsh[h] = ns / ssum;
                    }
#pragma unroll
                    for (int c = 0; c < 8; c++) {
                        int h = c >> 2;
                        float P = 0.f;
#pragma unroll
                        for (int l = 0; l < Li; l++) P = fmaf(e[h][l], xs[l * 8 + c], P);
                        T[c] = fmaf(nsh[h], P, T[c]);
                    }
                    SN += ns;
                }
            }
        }
    }
#pragma unroll
    for (int m2 = 1; m2 < 8; m2 <<= 1) {
#pragma unroll
        for (int c = 0; c < 8; c++) T[c] += __shfl_xor(T[c], m2);
        SN += __shfl_xor(SN, m2);
    }
    float nd = (Li == 1) ? *(const float*)(A + (size_t)d * 32 + 16)
                         : *(const float*)(U + (size_t)d * 64 + 48);
    if (!LAST) {
        float acc = fmaf(wv[t], T[t], bv[t] * SN);
        float h = fmaxf(acc * nd, 0.f);
        *(_Float16*)(U + (size_t)d * 64 + Li * 16 + 2 * t) = (_Float16)h;
    } else if (t == 0) {
        float z0 = b2[0], z1 = b2[1];
#pragma unroll
        for (int c = 0; c < 8; c++) {
            float acc = fmaf(wv[c], T[c], bv[c] * SN);
            float h = fmaxf(acc * nd, 0.f);
            z0 = fmaf(h, W2[c * 2 + 0], z0);
            z1 = fmaf(h, W2[c * 2 + 1], z1);
        }
        float m2 = fmaxf(z0, z1);
        float lse = m2 + logf(__expf(z0 - m2) + __expf(z1 - m2));
        ((float2*)out)[d] = make_float2(z0 - lse, z1 - lse);
    }
}

extern "C" void kernel_launch(void* const* d_in, const int* in_sizes, int n_in,
                              void* d_out, int out_size, void* d_ws, size_t ws_size,
                              hipStream_t stream) {
    const float* x    = (const float*)d_in[0];
    const int*   nidx = (const int*)d_in[1];
    const int*   eidx = (const int*)d_in[3];
    const float* emb  = (const float*)d_in[5];
    const float* W1   = (const float*)d_in[6];
    const float* b1   = (const float*)d_in[7];
    const float* Wq   = (const float*)d_in[8];
    const float* bq   = (const float*)d_in[9];
    const float* Wk   = (const float*)d_in[10];
    const float* bk   = (const float*)d_in[11];
    const float* Wv   = (const float*)d_in[12];
    const float* bv   = (const float*)d_in[13];
    const float* W2   = (const float*)d_in[14];
    const float* b2   = (const float*)d_in[15];
    float* out = (float*)d_out;

    const int n = in_sizes[0] / 16;            // 100000
    const int E = in_sizes[3] / 2;             // 3200000
    const int NS = (n + SBN - 1) / SBN;        // 391
    const int NBLK = (E + CH - 1) / CH;        // 782

    char* wsp = (char*)d_ws;
    char*  A     = wsp;                      wsp += (size_t)n * 32;
    char*  U     = wsp;                      wsp += (size_t)n * 64;
    int*   ebuf  = (int*)wsp;                wsp += (size_t)NS * CAP * 4;
    unsigned int* off = (unsigned int*)wsp;  wsp += (size_t)n * 4;
    int*   gcnt  = (int*)wsp;                wsp += (size_t)NS * 4;

    dim3 blk(256);
    dim3 gn((n + 255) / 256);
    dim3 ga(((size_t)n * 8 + 255) / 256);

    node_init<<<gn, blk, 0, stream>>>(x, nidx, emb, W1, b1, A, U, gcnt, NS, n);
    phaseAC<<<NBLK, blk, 0, stream>>>(eidx, gcnt, ebuf, E, NS);
    super_csr<<<NS, blk, 0, stream>>>(ebuf, gcnt, off, A, U, NS, n);

    agg_layer<1, false><<<ga, blk, 0, stream>>>(ebuf, off, A, U,
        Wq, bq, Wk, bk, Wv, bv, W2, b2, out, n);
    agg_layer<2, false><<<ga, blk, 0, stream>>>(ebuf, off, A, U,
        Wq + 8, bq + 8, Wk + 8, bk + 8, Wv + 8, bv + 8, W2, b2, out, n);
    agg_layer<3, true><<<ga, blk, 0, stream>>>(ebuf, off, A, U,
        Wq + 16, bq + 16, Wk + 16, bk + 16, Wv + 16, bv + 16, W2, b2, out, n);
}

// Round 16
// 266.534 us; speedup vs baseline: 1.5066x; 1.0227x over previous
//
#include <hip/hip_runtime.h>
#include <math.h>

// DNA-GNN: N=100000, E=3200000, C=8, HEADS=2, d_head=4, 3 layers.
// glin GROUPS=8, cin=cout=1 => per-channel scale+bias.
//
// Round 16: un-starve the gather pipeline.
//   agg_layer gets __launch_bounds__(256, 2): 2 waves/EU -> ~256 VGPR budget,
//   so B staged rows really stay in flight (r15 compiled at 60 VGPR and
//   serialized the 8-deep batch). B = 8 for all layers now.
//   Everything else as r15: r14 algebra (bk dropped, wv/bv in epilogue,
//   Li=1 attention-free), A (N,32B)+U (N,64B) tables, single-pass CSR build,
//   gcnt zeroed in node_init.

#define SBB   8
#define SBN   256
#define CH    4096
#define CAP   9216

typedef _Float16 half8 __attribute__((ext_vector_type(8)));
typedef int int4v __attribute__((ext_vector_type(4)));

__global__ void __launch_bounds__(256) phaseAC(const int* __restrict__ eidx,
                                               int* __restrict__ gcnt,
                                               int* __restrict__ ebuf,
                                               int E, int NS) {
    __shared__ int sorted_[CH];
    __shared__ unsigned short karr[CH];
    __shared__ int cntS[512];
    __shared__ int lofs[512];
    __shared__ int wbase[512];
    __shared__ int sA[512], sB[512];
    int t = threadIdx.x, b = blockIdx.x;
    int base = b * CH;
    int nEdge = E - base; if (nEdge > CH) nEdge = CH;

    for (int i = t; i < 512; i += 256) cntS[i] = 0;
    __syncthreads();

    int w[16]; short kk[16];
#pragma unroll
    for (int it = 0; it < 4; it++) {
        int e0 = base + (it * 256 + t) * 4;
        if (e0 + 3 < E) {
            int4v s4 = __builtin_nontemporal_load((const int4v*)(eidx + e0));
            int4v d4 = __builtin_nontemporal_load((const int4v*)(eidx + E + e0));
#pragma unroll
            for (int j = 0; j < 4; j++) {
                int idx = it * 4 + j;
                w[idx] = s4[j] | ((d4[j] & (SBN - 1)) << 17);
                kk[idx] = (short)(d4[j] >> SBB);
                atomicAdd(&cntS[kk[idx]], 1);
            }
        } else {
#pragma unroll
            for (int j = 0; j < 4; j++) {
                int e = e0 + j, idx = it * 4 + j;
                if (e < E) {
                    int s = eidx[e], d = eidx[E + e];
                    w[idx] = s | ((d & (SBN - 1)) << 17);
                    kk[idx] = (short)(d >> SBB);
                    atomicAdd(&cntS[kk[idx]], 1);
                } else { w[idx] = 0; kk[idx] = 511; }
            }
        }
    }
    __syncthreads();
    sA[t] = cntS[t]; sA[t + 256] = cntS[t + 256];
    __syncthreads();
    int* sp = sA; int* dp = sB;
    for (int o = 1; o < 512; o <<= 1) {
#pragma unroll
        for (int h = 0; h < 2; h++) {
            int i = t + h * 256;
            int v = sp[i];
            if (i >= o) v += sp[i - o];
            dp[i] = v;
        }
        __syncthreads();
        int* tmp = sp; sp = dp; dp = tmp;
    }
    for (int i = t; i < 512; i += 256) {
        int excl = sp[i] - cntS[i];
        lofs[i] = excl;
        if (i < NS && cntS[i] > 0) {
            int g = atomicAdd(&gcnt[i], cntS[i]);
            wbase[i] = i * CAP + g - excl;
        }
    }
    __syncthreads();
#pragma unroll
    for (int idx = 0; idx < 16; idx++) {
        if (kk[idx] != 511) {
            int p = atomicAdd(&lofs[kk[idx]], 1);
            sorted_[p] = w[idx];
            karr[p] = (unsigned short)kk[idx];
        }
    }
    __syncthreads();
    for (int i = t; i < nEdge; i += 256)
        ebuf[wbase[karr[i]] + i] = sorted_[i];
}

__global__ void super_csr(int* __restrict__ ebuf, const int* __restrict__ gcnt,
                          unsigned int* __restrict__ off, char* __restrict__ A,
                          char* __restrict__ U, int NS, int n) {
    __shared__ int seg[CAP];
    __shared__ int cnt[SBN];
    __shared__ int fillp[SBN];
    __shared__ int sd[256];
    int t = threadIdx.x, k = blockIdx.x;
    cnt[t] = 0;
    int start = k * CAP;
    int len = gcnt[k];
    __syncthreads();
    for (int i = t; i < len; i += 256) {
        int w = __builtin_nontemporal_load(&ebuf[start + i]);
        seg[i] = w;
        atomicAdd(&cnt[w >> 17], 1);
    }
    __syncthreads();
    int v = cnt[t];
    sd[t] = v; __syncthreads();
    for (int o = 1; o < 256; o <<= 1) {
        int u = 0; if (t >= o) u = sd[t - o];
        __syncthreads(); sd[t] += u; __syncthreads();
    }
    int excl = sd[t] - v;
    fillp[t] = excl;
    int d = (k << SBB) + t;
    if (d < n) {
        off[d] = (unsigned int)(start + excl) | ((unsigned int)v << 22);
        float dvv = rsqrtf((float)(v + 1));   // +1 self-loop
        *(float*)(A + (size_t)d * 32 + 16) = dvv;
        *(float*)(U + (size_t)d * 64 + 48) = dvv;
    }
    __syncthreads();
    for (int i = t; i < len; i += 256) {
        int w = seg[i];
        int pos = atomicAdd(&fillp[w >> 17], 1);
        ebuf[start + pos] = w & 131071;
    }
}

// h0 = relu([emb[nidx], x] @ W1 + b1) -> A and U ch0..7; also zeroes gcnt.
__global__ void node_init(const float* __restrict__ x, const int* __restrict__ nidx,
                          const float* __restrict__ emb, const float* __restrict__ W1,
                          const float* __restrict__ b1, char* __restrict__ A,
                          char* __restrict__ U, int* __restrict__ gcnt,
                          int NS, int n) {
    int i = blockIdx.x * blockDim.x + threadIdx.x;
    if (i < NS) gcnt[i] = 0;
    if (i >= n) return;
    float in[24];
    int ni = nidx[i];
    const float4* ep = (const float4*)(emb + (size_t)ni * 8);
    float4 e0 = ep[0], e1 = ep[1];
    in[0] = e0.x; in[1] = e0.y; in[2] = e0.z; in[3] = e0.w;
    in[4] = e1.x; in[5] = e1.y; in[6] = e1.z; in[7] = e1.w;
    const float4* xp = (const float4*)(x + (size_t)i * 16);
#pragma unroll
    for (int t = 0; t < 4; t++) {
        float4 v = xp[t];
        in[8 + 4 * t + 0] = v.x; in[8 + 4 * t + 1] = v.y;
        in[8 + 4 * t + 2] = v.z; in[8 + 4 * t + 3] = v.w;
    }
    float acc[8];
#pragma unroll
    for (int j = 0; j < 8; j++) acc[j] = b1[j];
#pragma unroll
    for (int t = 0; t < 24; t++) {
        float xv = in[t];
#pragma unroll
        for (int j = 0; j < 8; j++) acc[j] = fmaf(xv, W1[t * 8 + j], acc[j]);
    }
    half8 h;
#pragma unroll
    for (int j = 0; j < 8; j++) h[j] = (_Float16)fmaxf(acc[j], 0.0f);
    *(half8*)(A + (size_t)i * 32) = h;
    *(half8*)(U + (size_t)i * 64) = h;
}

// 8 lanes per dst; lane owns a contiguous slot chunk (slot 0 = virtual
// self-loop); batches of 8 slots -> 8 independent row gathers in flight.
// __launch_bounds__(256,2): ~256 VGPR budget so the staging really stays
// in registers (r15's default budget serialized it at 60 VGPR).
template <int Li, bool LAST>
__global__ void __launch_bounds__(256, 2)
agg_layer(const int* __restrict__ ssrc, const unsigned int* __restrict__ off,
          const char* __restrict__ A, char* __restrict__ U,
          const float* __restrict__ wq, const float* __restrict__ bq,
          const float* __restrict__ wk, const float* __restrict__ bk,
          const float* __restrict__ wv, const float* __restrict__ bv,
          const float* __restrict__ W2, const float* __restrict__ b2,
          float* __restrict__ out, int n) {
    constexpr int B = 8;
    int tid = blockIdx.x * blockDim.x + threadIdx.x;
    int d = tid >> 3, t = tid & 7;
    if (d >= n) return;
    unsigned int ow = off[d];
    int lo = (int)(ow & 0x3FFFFFu), cnt = (int)(ow >> 22);

    float qk[8];
    if (Li >= 2) {
        half8 qh = (Li == 2) ? *(const half8*)(U + (size_t)d * 64 + 16)
                             : *(const half8*)(U + (size_t)d * 64 + 32);
#pragma unroll
        for (int c = 0; c < 8; c++) {
            float qv = fmaf((float)qh[c], wq[c], bq[c]);
            qk[c] = 0.5f * wk[c] * qv;     // bk drops out of softmax
        }
    }

    float T[8]; float SN = 0.f;
#pragma unroll
    for (int c = 0; c < 8; c++) T[c] = 0.f;

    int total = cnt + 1;
    int g = (total + 7) >> 3;
    int j0 = t * g;
    int j1 = j0 + g; if (j1 > total) j1 = total;

    for (int j = j0; j < j1; j += B) {
        int m = j1 - j; if (m > B) m = B;
        int sidx[B];
#pragma unroll
        for (int u = 0; u < B; u++) {
            int idx = j + u;
            sidx[u] = (u < m) ? ((idx == 0) ? d : ssrc[lo + idx - 1]) : d;
        }
        half8 r[B][Li]; float nsv[B];
#pragma unroll
        for (int u = 0; u < B; u++) {
            if (u < m) {
                if (Li == 1) {
                    const char* p = A + (size_t)sidx[u] * 32;
                    r[u][0] = *(const half8*)p;
                    nsv[u] = *(const float*)(p + 16);
                } else {
                    const char* p = U + (size_t)sidx[u] * 64;
#pragma unroll
                    for (int l = 0; l < Li; l++) r[u][l] = *(const half8*)(p + l * 16);
                    nsv[u] = *(const float*)(p + 48);
                }
            }
        }
#pragma unroll
        for (int u = 0; u < B; u++) {
            if (u < m) {
                float xs[8 * Li];
#pragma unroll
                for (int l = 0; l < Li; l++)
#pragma unroll
                    for (int c = 0; c < 8; c++) xs[l * 8 + c] = (float)r[u][l][c];
                float ns = nsv[u];
                if (Li == 1) {
#pragma unroll
                    for (int c = 0; c < 8; c++) T[c] = fmaf(ns, xs[c], T[c]);
                    SN += ns;
                } else {
                    float score[2][Li];
#pragma unroll
                    for (int l = 0; l < Li; l++) {
#pragma unroll
                        for (int h = 0; h < 2; h++) {
                            float sc = 0.f;
#pragma unroll
                            for (int dd = 0; dd < 4; dd++) {
                                int c = h * 4 + dd;
                                sc = fmaf(qk[c], xs[l * 8 + c], sc);
                            }
                            score[h][l] = sc;
                        }
                    }
                    float e[2][Li], nsh[2];
#pragma unroll
                    for (int h = 0; h < 2; h++) {
                        float mx = score[h][0];
#pragma unroll
                        for (int l = 1; l < Li; l++) mx = fmaxf(mx, score[h][l]);
                        float ssum = 0.f;
#pragma unroll
                        for (int l = 0; l < Li; l++) { e[h][l] = __expf(score[h][l] - mx); ssum += e[h][l]; }
                        nsh[h] = ns / ssum;
                    }
#pragma unroll
                    for (int c = 0; c < 8; c++) {
                        int h = c >> 2;
                        float P = 0.f;
#pragma unroll
                        for (int l = 0; l < Li; l++) P = fmaf(e[h][l], xs[l * 8 + c], P);
                        T[c] = fmaf(nsh[h], P, T[c]);
                    }
                    SN += ns;
                }
            }
        }
    }
#pragma unroll
    for (int m2 = 1; m2 < 8; m2 <<= 1) {
#pragma unroll
        for (int c = 0; c < 8; c++) T[c] += __shfl_xor(T[c], m2);
        SN += __shfl_xor(SN, m2);
    }
    float nd = (Li == 1) ? *(const float*)(A + (size_t)d * 32 + 16)
                         : *(const float*)(U + (size_t)d * 64 + 48);
    if (!LAST) {
        float acc = fmaf(wv[t], T[t], bv[t] * SN);
        float h = fmaxf(acc * nd, 0.f);
        *(_Float16*)(U + (size_t)d * 64 + Li * 16 + 2 * t) = (_Float16)h;
    } else if (t == 0) {
        float z0 = b2[0], z1 = b2[1];
#pragma unroll
        for (int c = 0; c < 8; c++) {
            float acc = fmaf(wv[c], T[c], bv[c] * SN);
            float h = fmaxf(acc * nd, 0.f);
            z0 = fmaf(h, W2[c * 2 + 0], z0);
            z1 = fmaf(h, W2[c * 2 + 1], z1);
        }
        float m2 = fmaxf(z0, z1);
        float lse = m2 + logf(__expf(z0 - m2) + __expf(z1 - m2));
        ((float2*)out)[d] = make_float2(z0 - lse, z1 - lse);
    }
}

extern "C" void kernel_launch(void* const* d_in, const int* in_sizes, int n_in,
                              void* d_out, int out_size, void* d_ws, size_t ws_size,
                              hipStream_t stream) {
    const float* x    = (const float*)d_in[0];
    const int*   nidx = (const int*)d_in[1];
    const int*   eidx = (const int*)d_in[3];
    const float* emb  = (const float*)d_in[5];
    const float* W1   = (const float*)d_in[6];
    const float* b1   = (const float*)d_in[7];
    const float* Wq   = (const float*)d_in[8];
    const float* bq   = (const float*)d_in[9];
    const float* Wk   = (const float*)d_in[10];
    const float* bk   = (const float*)d_in[11];
    const float* Wv   = (const float*)d_in[12];
    const float* bv   = (const float*)d_in[13];
    const float* W2   = (const float*)d_in[14];
    const float* b2   = (const float*)d_in[15];
    float* out = (float*)d_out;

    const int n = in_sizes[0] / 16;            // 100000
    const int E = in_sizes[3] / 2;             // 3200000
    const int NS = (n + SBN - 1) / SBN;        // 391
    const int NBLK = (E + CH - 1) / CH;        // 782

    char* wsp = (char*)d_ws;
    char*  A     = wsp;                      wsp += (size_t)n * 32;
    char*  U     = wsp;                      wsp += (size_t)n * 64;
    int*   ebuf  = (int*)wsp;                wsp += (size_t)NS * CAP * 4;
    unsigned int* off = (unsigned int*)wsp;  wsp += (size_t)n * 4;
    int*   gcnt  = (int*)wsp;                wsp += (size_t)NS * 4;

    dim3 blk(256);
    dim3 gn((n + 255) / 256);
    dim3 ga(((size_t)n * 8 + 255) / 256);

    node_init<<<gn, blk, 0, stream>>>(x, nidx, emb, W1, b1, A, U, gcnt, NS, n);
    phaseAC<<<NBLK, blk, 0, stream>>>(eidx, gcnt, ebuf, E, NS);
    super_csr<<<NS, blk, 0, stream>>>(ebuf, gcnt, off, A, U, NS, n);

    agg_layer<1, false><<<ga, blk, 0, stream>>>(ebuf, off, A, U,
        Wq, bq, Wk, bk, Wv, bv, W2, b2, out, n);
    agg_layer<2, false><<<ga, blk, 0, stream>>>(ebuf, off, A, U,
        Wq + 8, bq + 8, Wk + 8, bk + 8, Wv + 8, bv + 8, W2, b2, out, n);
    agg_layer<3, true><<<ga, blk, 0, stream>>>(ebuf, off, A, U,
        Wq + 16, bq + 16, Wk + 16, bk + 16, Wv + 16, bv + 16, W2, b2, out, n);
}